// Round 8
// baseline (209.586 us; speedup 1.0000x reference)
//
#include <hip/hip_runtime.h>
#include <hip/hip_fp16.h>

// Fused Sinkhorn OT. n=64, in_size=1024, in_dim=128, heads=4, out_size=64.
// Single kernel, 256 blocks x 1024 threads (1 block/CU):
//   P1: K-GEMM (fp32 pk-fma, W^T staged LDS) -> EK=exp(K) in regs (8x8/thread)
//   P2: multiplicative Sinkhorn, ONE barrier/iter: DPP/swizzle/xor32 column
//       reduce -> cw[16][68] -> barrier -> ALL waves redundantly sum the 16
//       partials (identical -> identical per-wave ballot convergence, ev in
//       regs, ep via ds_bpermute). Early exit tol 1e-4, cap 100.
//   P3: out = T^T x on MFMA f32_16x16x32_f16. LDS rows padded to 264 halfs
//       (528B = 4-bank shift/row) -> all b128 accesses uniform 8 lanes/quad
//       (structural floor), no swizzle. x staged via per-lane-d coalesced b32
//       loads (no reg transpose); 256-i chunks; next chunk's loads issued
//       before the MFMA block.

typedef _Float16 half8 __attribute__((ext_vector_type(8)));
typedef float f32x4 __attribute__((ext_vector_type(4)));

__device__ __forceinline__ float2 pkfma(float2 a, float2 b, float2 c) {
  return make_float2(fmaf(a.x, b.x, c.x), fmaf(a.y, b.y, c.y));
}

template <int CTRL>
__device__ __forceinline__ float dpp_add(float v) {
  return v + __int_as_float(__builtin_amdgcn_update_dpp(
                 0, __float_as_int(v), CTRL, 0xf, 0xf, true));
}
__device__ __forceinline__ float swz16_add(float v) {
  return v + __int_as_float(
                 __builtin_amdgcn_ds_swizzle(__float_as_int(v), 0x401F));
}
__device__ __forceinline__ float bperm(int srclane, float v) {
  return __int_as_float(
      __builtin_amdgcn_ds_bpermute(srclane << 2, __float_as_int(v)));
}

// XCD-aware batch map: 4 heads of one nb + 8 nb per XCD (4 MB x-slice = L2).
__device__ __forceinline__ void batch_map(int bb, int& nb, int& m) {
  int k = bb >> 3;
  nb = 8 * (bb & 7) + (k >> 2);
  m = k & 3;
}

__global__ __launch_bounds__(1024, 4) void ot_fused_kernel(
    const float* __restrict__ x, const float* __restrict__ w,
    float* __restrict__ out) {
  int nb, m;
  batch_map(blockIdx.x, nb, m);
  const int t = threadIdx.x;
  const int gi = t >> 3;  // rows 8*gi..8*gi+7
  const int gj = t & 7;   // cols 8*gj..8*gj+7
  const int lane = t & 63;
  const int wvw = t >> 6;  // wave 0..15

  __shared__ union {
    float wt[128][68];  // P1 staging
    float cw[16][68];   // P2 per-wave col partials
    struct {
      __half Xh[128 * 264];  // P3 x chunk, [d][i-local], stride 264
      __half To[64 * 264];   // P3 T chunk, [o][i-local], stride 264
    } p3;                    // ~101 KB
  } u_;

  // ---- P1a: stage W^T ----
  const float* wm = w + (size_t)m * 64 * 128;
  for (int e = t; e < 64 * 128; e += 1024) {
    int j = e >> 7, d = e & 127;
    u_.wt[d][j] = wm[e];
  }
  __syncthreads();

  // ---- P1b: K tile (8x8/thread), EK = exp(K) ----
  float2 E2[8][4];
  #pragma unroll
  for (int r = 0; r < 8; ++r)
    #pragma unroll
    for (int c = 0; c < 4; ++c) E2[r][c] = make_float2(0.f, 0.f);

  const float* xrow = x + (size_t)nb * 1024 * 128 + (size_t)gi * 8 * 128;
  for (int d = 0; d < 128; d += 4) {
    float2 wr[4][4];
    #pragma unroll
    for (int dd = 0; dd < 4; ++dd) {
      float4 a0 = *(const float4*)&u_.wt[d + dd][8 * gj];
      float4 a1 = *(const float4*)&u_.wt[d + dd][8 * gj + 4];
      wr[dd][0] = make_float2(a0.x, a0.y);
      wr[dd][1] = make_float2(a0.z, a0.w);
      wr[dd][2] = make_float2(a1.x, a1.y);
      wr[dd][3] = make_float2(a1.z, a1.w);
    }
    #pragma unroll
    for (int r = 0; r < 8; ++r) {
      float4 xv = *(const float4*)&xrow[r * 128 + d];
      float xs[4] = {xv.x, xv.y, xv.z, xv.w};
      #pragma unroll
      for (int dd = 0; dd < 4; ++dd)
        #pragma unroll
        for (int c = 0; c < 4; ++c)
          E2[r][c] = pkfma(make_float2(xs[dd], xs[dd]), wr[dd][c], E2[r][c]);
    }
  }
  #pragma unroll
  for (int r = 0; r < 8; ++r)
    #pragma unroll
    for (int c = 0; c < 4; ++c) {
      E2[r][c].x = __expf(E2[r][c].x);
      E2[r][c].y = __expf(E2[r][c].y);
    }
  __syncthreads();

  // ---- P2: Sinkhorn, ONE barrier/iter, ev in regs, per-wave convergence ----
  float ur[8];
  float evj = 1.0f;  // ev for column j==lane (per-wave redundant copy)
  float2 ep[4] = {make_float2(1.f, 1.f), make_float2(1.f, 1.f),
                  make_float2(1.f, 1.f), make_float2(1.f, 1.f)};
  for (int it = 0; it < 100; ++it) {
    // (A) row sums + DPP butterfly over gj -> ur
    #pragma unroll
    for (int r = 0; r < 8; ++r) {
      float2 a = make_float2(0.f, 0.f);
      #pragma unroll
      for (int c = 0; c < 4; ++c) a = pkfma(E2[r][c], ep[c], a);
      float sr = a.x + a.y;
      sr = dpp_add<0xB1>(sr);
      sr = dpp_add<0x4E>(sr);
      sr = dpp_add<0x141>(sr);
      ur[r] = 0.0625f * __builtin_amdgcn_rcpf(sr);
    }
    // (B) col partials; xor8+xor16+xor32 -> per-wave partial, write cw
    float2 tp[4] = {make_float2(0.f, 0.f), make_float2(0.f, 0.f),
                    make_float2(0.f, 0.f), make_float2(0.f, 0.f)};
    #pragma unroll
    for (int r = 0; r < 8; ++r) {
      float2 uu = make_float2(ur[r], ur[r]);
      #pragma unroll
      for (int c = 0; c < 4; ++c) tp[c] = pkfma(E2[r][c], uu, tp[c]);
    }
    float tv[8] = {tp[0].x, tp[0].y, tp[1].x, tp[1].y,
                   tp[2].x, tp[2].y, tp[3].x, tp[3].y};
    #pragma unroll
    for (int k = 0; k < 8; ++k) {
      tv[k] = dpp_add<0x128>(tv[k]);
      tv[k] = swz16_add(tv[k]);
      tv[k] += __shfl_xor(tv[k], 32, 64);
    }
    if (lane < 8) {
      *(float4*)&u_.cw[wvw][8 * lane] =
          make_float4(tv[0], tv[1], tv[2], tv[3]);
      *(float4*)&u_.cw[wvw][8 * lane + 4] =
          make_float4(tv[4], tv[5], tv[6], tv[7]);
    }
    __syncthreads();
    // (C) every wave: full column sum for j=lane, ev update, ballot check
    float ss = 0.f;
    #pragma unroll
    for (int p = 0; p < 16; ++p) ss += u_.cw[p][lane];
    unsigned long long bad = __ballot(fabsf(fmaf(ss, evj, -1.0f)) > 1e-4f);
    evj = __builtin_amdgcn_rcpf(ss);
    // redistribute: ep[c] = (ev[8gj+2c], ev[8gj+2c+1]) via bpermute
    #pragma unroll
    for (int c = 0; c < 4; ++c) {
      ep[c].x = bperm(8 * gj + 2 * c, evj);
      ep[c].y = bperm(8 * gj + 2 * c + 1, evj);
    }
    __syncthreads();  // cw consumed; writable next iter (also P3 reuse gate)
    if (bad == 0ULL) break;
  }

  // ---- P3 prologue: scale T, pack to f16 regs hhT (E2 dies here) ----
  #pragma unroll
  for (int r = 0; r < 8; ++r) {
    float2 uu = make_float2(ur[r], ur[r]);
    #pragma unroll
    for (int c = 0; c < 4; ++c) {
      E2[r][c].x = E2[r][c].x * uu.x * ep[c].x;
      E2[r][c].y = E2[r][c].y * uu.y * ep[c].y;
    }
  }
  __half2 hhT[8][4];  // hhT[co][q] = (T[2q][co], T[2q+1][co])
  #pragma unroll
  for (int co = 0; co < 8; ++co)
    #pragma unroll
    for (int q = 0; q < 4; ++q) {
      float va = (co & 1) ? E2[2 * q][co >> 1].y : E2[2 * q][co >> 1].x;
      float vb =
          (co & 1) ? E2[2 * q + 1][co >> 1].y : E2[2 * q + 1][co >> 1].x;
      hhT[co][q] = __float22half2_rn(make_float2(va, vb));
    }

  // ---- P3: out = T^T x via MFMA, 256-i chunks, pad-264 conflict-free ----
  const int dth = lane + 64 * (wvw & 1);  // this thread's d (x-stager)
  const int obase = wvw >> 1;             // oct base 0..7
  const int ml = lane & 15;
  const int kq = lane >> 4;
  const int ota = wvw & 3;
  const int dtb = wvw >> 2;
  const int oA = 16 * ota + ml;
  const int d0 = 32 * dtb + ml;
  const int d1 = d0 + 16;

  f32x4 acc0 = {0.f, 0.f, 0.f, 0.f}, acc1 = {0.f, 0.f, 0.f, 0.f};
  const float* xb = x + (size_t)nb * 1024 * 128;

  float xv[4][8];  // 4 cells (octs obase+8j), 8 i's each, at column dth
  // issue chunk 0 loads
  #pragma unroll
  for (int j = 0; j < 4; ++j) {
    const int oct = obase + 8 * j;
    const float* xs = xb + (size_t)(8 * oct) * 128 + dth;
    #pragma unroll
    for (int e = 0; e < 8; ++e) xv[j][e] = xs[(size_t)e * 128];
  }

  for (int ch = 0; ch < 4; ++ch) {
    __syncthreads();  // previous chunk's MFMA done (buffers free)
    // stage x: 4 cells -> b128 each at Xh[dth][8*oct]
    #pragma unroll
    for (int j = 0; j < 4; ++j) {
      const int oct = obase + 8 * j;
      __half2 hh[4];
      #pragma unroll
      for (int q = 0; q < 4; ++q)
        hh[q] = __float22half2_rn(make_float2(xv[j][2 * q], xv[j][2 * q + 1]));
      *(uint4*)&u_.p3.Xh[dth * 264 + 8 * oct] = *(uint4*)hh;
    }
    // stage T: producers whose rows live in this chunk
    if ((t >> 8) == ch) {
      const int g = gi & 31;
      #pragma unroll
      for (int co = 0; co < 8; ++co) {
        const int o = 8 * gj + co;
        *(uint4*)&u_.p3.To[o * 264 + 8 * g] = *(const uint4*)&hhT[co][0];
      }
    }
    __syncthreads();
    // issue next chunk's loads (fly during MFMA)
    if (ch < 3) {
      #pragma unroll
      for (int j = 0; j < 4; ++j) {
        const int oct = obase + 8 * j;
        const float* xs =
            xb + (size_t)(256 * (ch + 1) + 8 * oct) * 128 + dth;
        #pragma unroll
        for (int e = 0; e < 8; ++e) xv[j][e] = xs[(size_t)e * 128];
      }
    }
    // MFMA: 8 K-steps of 32
    #pragma unroll
    for (int s = 0; s < 8; ++s) {
      const int ok = 4 * s + kq;  // i-oct for this fragment
      half8 af = *(const half8*)&u_.p3.To[oA * 264 + 8 * ok];
      half8 b0 = *(const half8*)&u_.p3.Xh[d0 * 264 + 8 * ok];
      half8 b1 = *(const half8*)&u_.p3.Xh[d1 * 264 + 8 * ok];
      acc0 = __builtin_amdgcn_mfma_f32_16x16x32_f16(af, b0, acc0, 0, 0, 0);
      acc1 = __builtin_amdgcn_mfma_f32_16x16x32_f16(af, b1, acc1, 0, 0, 0);
    }
  }

  // ---- store: C tile row = o (4*kq+rg), col = d (ml) ----
  #pragma unroll
  for (int rg = 0; rg < 4; ++rg) {
    const int o = 16 * ota + 4 * kq + rg;
    float* op = out + ((size_t)nb * 64 + o) * 512 + m * 128;
    op[d0] = acc0[rg];
    op[d1] = acc1[rg];
  }
}

extern "C" void kernel_launch(void* const* d_in, const int* in_sizes, int n_in,
                              void* d_out, int out_size, void* d_ws, size_t ws_size,
                              hipStream_t stream) {
  const float* x = (const float*)d_in[0];  // [64][1024][128] fp32
  const float* w = (const float*)d_in[1];  // [4][64][128] fp32
  float* out = (float*)d_out;              // [64][64][512] fp32
  ot_fused_kernel<<<256, 1024, 0, stream>>>(x, w, out);
}

// Round 9
// 172.652 us; speedup vs baseline: 1.2139x; 1.2139x over previous
//
#include <hip/hip_runtime.h>
#include <hip/hip_fp16.h>

// Fused Sinkhorn OT. n=64, in_size=1024, in_dim=128, heads=4, out_size=64.
// Single kernel, 256 blocks x 1024 threads (1 block/CU):
//   P1: K-GEMM (fp32 pk-fma, W^T staged LDS) -> EK=exp(K) in regs (8x8/thread)
//   P2: multiplicative Sinkhorn, ONE barrier/iter. Cross-lane reductions on
//       the VALU pipe: xor1/2/4 quad-DPP, xor8 row_ror:8 DPP, xor16/xor32 via
//       gfx950 v_permlane16/32_swap (DS-pipe-free; __has_builtin fallback).
//       cw parity-double-buffered; ev redistributed via per-wave-private evL
//       row (same-wave, no barrier). Early exit tol 1e-4, cap 100.
//   P3: out = T^T x on MFMA f32_16x16x32_f16, R7 structure: double-buffered
//       128-row chunks, T pre-packed to f16 regs (hhT), next chunk's x loads
//       issued before the MFMA block (no regs live across barriers -> no
//       spills).

typedef _Float16 half8 __attribute__((ext_vector_type(8)));
typedef float f32x4 __attribute__((ext_vector_type(4)));
typedef unsigned uint2v __attribute__((ext_vector_type(2)));

__device__ __forceinline__ float2 pkfma(float2 a, float2 b, float2 c) {
  return make_float2(fmaf(a.x, b.x, c.x), fmaf(a.y, b.y, c.y));
}

template <int CTRL>
__device__ __forceinline__ float dpp_add(float v) {
  return v + __int_as_float(__builtin_amdgcn_update_dpp(
                 0, __float_as_int(v), CTRL, 0xf, 0xf, true));
}

// xor16 / xor32 butterfly adds. VALU-pipe permlane swaps on gfx950;
// DS-pipe fallbacks otherwise.
#if __has_builtin(__builtin_amdgcn_permlane16_swap)
__device__ __forceinline__ float x16_add(float v) {
  uint2v r = __builtin_amdgcn_permlane16_swap(__float_as_uint(v),
                                              __float_as_uint(v), false,
                                              false);
  return __uint_as_float(r.x) + __uint_as_float(r.y);
}
#else
__device__ __forceinline__ float x16_add(float v) {
  return v + __int_as_float(
                 __builtin_amdgcn_ds_swizzle(__float_as_int(v), 0x401F));
}
#endif
#if __has_builtin(__builtin_amdgcn_permlane32_swap)
__device__ __forceinline__ float x32_add(float v) {
  uint2v r = __builtin_amdgcn_permlane32_swap(__float_as_uint(v),
                                              __float_as_uint(v), false,
                                              false);
  return __uint_as_float(r.x) + __uint_as_float(r.y);
}
#else
__device__ __forceinline__ float x32_add(float v) {
  return v + __shfl_xor(v, 32, 64);
}
#endif

// XCD-aware batch map: 4 heads of one nb + 8 nb per XCD (4 MB x-slice = L2).
__device__ __forceinline__ void batch_map(int bb, int& nb, int& m) {
  int k = bb >> 3;
  nb = 8 * (bb & 7) + (k >> 2);
  m = k & 3;
}

__global__ __launch_bounds__(1024, 4) void ot_fused_kernel(
    const float* __restrict__ x, const float* __restrict__ w,
    float* __restrict__ out) {
  int nb, m;
  batch_map(blockIdx.x, nb, m);
  const int t = threadIdx.x;
  const int gi = t >> 3;  // rows 8*gi..8*gi+7
  const int gj = t & 7;   // cols 8*gj..8*gj+7
  const int lane = t & 63;
  const int wvw = t >> 6;  // wave 0..15

  __shared__ union {
    float wt[128][68];  // P1 staging
    struct {
      __half Xh[2][128 * 128];  // P3 x chunks, f16, [d][i-local] swizzled
      __half To[2][64 * 128];   // P3 T chunks, f16, [o][i-local] swizzled
    } p3;                       // 96 KB
  } u_;
  __shared__ float cw[2][16][68];  // P2 col partials, parity-buffered
  __shared__ float evL[16][68];    // per-wave-private ev copies

  // ---- P1a: stage W^T ----
  const float* wm = w + (size_t)m * 64 * 128;
  for (int e = t; e < 64 * 128; e += 1024) {
    int j = e >> 7, d = e & 127;
    u_.wt[d][j] = wm[e];
  }
  __syncthreads();

  // ---- P1b: K tile (8x8/thread), EK = exp(K) ----
  float2 E2[8][4];
  #pragma unroll
  for (int r = 0; r < 8; ++r)
    #pragma unroll
    for (int c = 0; c < 4; ++c) E2[r][c] = make_float2(0.f, 0.f);

  const float* xrow = x + (size_t)nb * 1024 * 128 + (size_t)gi * 8 * 128;
  for (int d = 0; d < 128; d += 4) {
    float2 wr[4][4];
    #pragma unroll
    for (int dd = 0; dd < 4; ++dd) {
      float4 a0 = *(const float4*)&u_.wt[d + dd][8 * gj];
      float4 a1 = *(const float4*)&u_.wt[d + dd][8 * gj + 4];
      wr[dd][0] = make_float2(a0.x, a0.y);
      wr[dd][1] = make_float2(a0.z, a0.w);
      wr[dd][2] = make_float2(a1.x, a1.y);
      wr[dd][3] = make_float2(a1.z, a1.w);
    }
    #pragma unroll
    for (int r = 0; r < 8; ++r) {
      float4 xv = *(const float4*)&xrow[r * 128 + d];
      float xs[4] = {xv.x, xv.y, xv.z, xv.w};
      #pragma unroll
      for (int dd = 0; dd < 4; ++dd)
        #pragma unroll
        for (int c = 0; c < 4; ++c)
          E2[r][c] = pkfma(make_float2(xs[dd], xs[dd]), wr[dd][c], E2[r][c]);
    }
  }
  #pragma unroll
  for (int r = 0; r < 8; ++r)
    #pragma unroll
    for (int c = 0; c < 4; ++c) {
      E2[r][c].x = __expf(E2[r][c].x);
      E2[r][c].y = __expf(E2[r][c].y);
    }
  __syncthreads();

  // ---- P2: Sinkhorn, 1 barrier/iter, VALU-pipe reductions ----
  float ur[8];
  float evj = 1.0f;  // ev for column j==lane (per-wave redundant copy)
  float2 ep[4] = {make_float2(1.f, 1.f), make_float2(1.f, 1.f),
                  make_float2(1.f, 1.f), make_float2(1.f, 1.f)};
  for (int it = 0; it < 100; ++it) {
    const int pb = it & 1;
    // (A) row sums: in-thread pk-dot + xor1/2/4 quad-DPP over gj
    #pragma unroll
    for (int r = 0; r < 8; ++r) {
      float2 a = make_float2(0.f, 0.f);
      #pragma unroll
      for (int c = 0; c < 4; ++c) a = pkfma(E2[r][c], ep[c], a);
      float sr = a.x + a.y;
      sr = dpp_add<0xB1>(sr);
      sr = dpp_add<0x4E>(sr);
      sr = dpp_add<0x141>(sr);
      ur[r] = 0.0625f * __builtin_amdgcn_rcpf(sr);
    }
    // (B) col partials: in-thread over 8 rows, then xor8 (DPP) + xor16/xor32
    //     (permlane swaps, VALU) -> full wave col-sum at every lane
    float2 tp[4] = {make_float2(0.f, 0.f), make_float2(0.f, 0.f),
                    make_float2(0.f, 0.f), make_float2(0.f, 0.f)};
    #pragma unroll
    for (int r = 0; r < 8; ++r) {
      float2 uu = make_float2(ur[r], ur[r]);
      #pragma unroll
      for (int c = 0; c < 4; ++c) tp[c] = pkfma(E2[r][c], uu, tp[c]);
    }
    float tv[8] = {tp[0].x, tp[0].y, tp[1].x, tp[1].y,
                   tp[2].x, tp[2].y, tp[3].x, tp[3].y};
    #pragma unroll
    for (int k = 0; k < 8; ++k) {
      tv[k] = dpp_add<0x128>(tv[k]);  // xor8 within 16 (row_ror:8)
      tv[k] = x16_add(tv[k]);         // xor16 (VALU permlane swap)
      tv[k] = x32_add(tv[k]);         // xor32 (VALU permlane swap)
    }
    if (lane < 8) {  // lane==gj covers all 64 cols
      *(float4*)&cw[pb][wvw][8 * lane] =
          make_float4(tv[0], tv[1], tv[2], tv[3]);
      *(float4*)&cw[pb][wvw][8 * lane + 4] =
          make_float4(tv[4], tv[5], tv[6], tv[7]);
    }
    __syncthreads();
    // (C) every wave: sum 16 partials for col=lane, ballot, redistribute
    //     via per-wave-private evL row (same-wave: no barrier needed)
    float ss = 0.f;
    #pragma unroll
    for (int p = 0; p < 16; ++p) ss += cw[pb][p][lane];
    unsigned long long bad = __ballot(fabsf(fmaf(ss, evj, -1.0f)) > 1e-4f);
    evj = __builtin_amdgcn_rcpf(ss);
    evL[wvw][lane] = evj;
    float4 e0 = *(const float4*)&evL[wvw][8 * gj];
    float4 e1 = *(const float4*)&evL[wvw][8 * gj + 4];
    ep[0] = make_float2(e0.x, e0.y);
    ep[1] = make_float2(e0.z, e0.w);
    ep[2] = make_float2(e1.x, e1.y);
    ep[3] = make_float2(e1.z, e1.w);
    if (bad == 0ULL) break;
  }

  // ---- P3 prologue: scale T, pack to f16 regs hhT (E2 dies here) ----
  #pragma unroll
  for (int r = 0; r < 8; ++r) {
    float2 uu = make_float2(ur[r], ur[r]);
    #pragma unroll
    for (int c = 0; c < 4; ++c) {
      E2[r][c].x = E2[r][c].x * uu.x * ep[c].x;
      E2[r][c].y = E2[r][c].y * uu.y * ep[c].y;
    }
  }
  __half2 hhT[8][4];  // hhT[co][q] = (T[2q][co], T[2q+1][co])
  #pragma unroll
  for (int co = 0; co < 8; ++co)
    #pragma unroll
    for (int q = 0; q < 4; ++q) {
      float va = (co & 1) ? E2[2 * q][co >> 1].y : E2[2 * q][co >> 1].x;
      float vb =
          (co & 1) ? E2[2 * q + 1][co >> 1].y : E2[2 * q + 1][co >> 1].x;
      hhT[co][q] = __float22half2_rn(make_float2(va, vb));
    }

  // ---- P3: out = T^T x via MFMA, double-buffered 128-row chunks ----
  const int ig4 = t >> 5;    // i-quad group 0..31 (rows 4*ig4..+3 of chunk)
  const int dq = t & 31;     // d-quad
  const int o8w = ig4 >> 1;  // logical i-oct of this stager
  const int hw = ig4 & 1;    // half within oct
  const int ml = lane & 15;
  const int kq = lane >> 4;
  const int ota = wvw & 3;
  const int dtb = wvw >> 2;
  const int oA = 16 * ota + ml;
  const int d0 = 32 * dtb + ml;
  const int d1 = d0 + 16;
  const int swA = oA & 15;
  const int swB0 = ((d0 >> 2) & 15) ^ ((d0 & 3) << 2);
  const int swB1 = ((d1 >> 2) & 15) ^ ((d1 & 3) << 2);

  f32x4 acc0 = {0.f, 0.f, 0.f, 0.f}, acc1 = {0.f, 0.f, 0.f, 0.f};
  const float* xb = x + (size_t)nb * 1024 * 128;

  auto stage_x = [&](int p, const float4* xv) {
    #pragma unroll
    for (int k = 0; k < 4; ++k) {
      const float* f0 = (const float*)&xv[0];
      const float* f1 = (const float*)&xv[1];
      const float* f2 = (const float*)&xv[2];
      const float* f3 = (const float*)&xv[3];
      __half2 hp[2];
      hp[0] = __float22half2_rn(make_float2(f0[k], f1[k]));
      hp[1] = __float22half2_rn(make_float2(f2[k], f3[k]));
      const int d = 4 * dq + k;
      const int pos = (o8w ^ (dq & 15) ^ (k << 2)) & 15;
      *(uint2*)&u_.p3.Xh[p][d * 128 + pos * 8 + hw * 4] = *(uint2*)hp;
    }
  };
  auto stage_T = [&](int c, int p) {
    if ((t >> 7) == c) {  // this thread's 8 rows live in chunk c
      const int g = gi & 15;
      #pragma unroll
      for (int co = 0; co < 8; ++co) {
        const int o = 8 * gj + co;
        const int pos = (g ^ (o & 15)) & 15;
        *(uint4*)&u_.p3.To[p][o * 128 + pos * 8] = *(const uint4*)&hhT[co][0];
      }
    }
  };

  // prologue: stage chunk 0 into buf 0
  {
    float4 xv[4];
    const float* xs = xb + (size_t)(4 * ig4) * 128 + 4 * dq;
    #pragma unroll
    for (int r = 0; r < 4; ++r) xv[r] = *(const float4*)(xs + r * 128);
    stage_x(0, xv);
    stage_T(0, 0);
  }
  __syncthreads();

  for (int c = 0; c < 8; ++c) {
    const int p = c & 1;
    float4 xv[4];
    if (c < 7) {  // issue next chunk's loads; complete under MFMA below
      const float* xs = xb + (size_t)(128 * (c + 1) + 4 * ig4) * 128 + 4 * dq;
      #pragma unroll
      for (int r = 0; r < 4; ++r) xv[r] = *(const float4*)(xs + r * 128);
    }
    // MFMA on current buffer: 4 K-steps of 32
    #pragma unroll
    for (int s = 0; s < 4; ++s) {
      const int gk = 4 * s + kq;
      half8 af =
          *(const half8*)&u_.p3.To[p][oA * 128 + ((gk ^ swA) & 15) * 8];
      half8 b0 =
          *(const half8*)&u_.p3.Xh[p][d0 * 128 + ((gk ^ swB0) & 15) * 8];
      half8 b1 =
          *(const half8*)&u_.p3.Xh[p][d1 * 128 + ((gk ^ swB1) & 15) * 8];
      acc0 = __builtin_amdgcn_mfma_f32_16x16x32_f16(af, b0, acc0, 0, 0, 0);
      acc1 = __builtin_amdgcn_mfma_f32_16x16x32_f16(af, b1, acc1, 0, 0, 0);
    }
    if (c < 7) {
      stage_x(p ^ 1, xv);
      stage_T(c + 1, p ^ 1);
    }
    __syncthreads();
  }

  // ---- store: C tile row = o (4*kq+rg), col = d (ml) ----
  #pragma unroll
  for (int rg = 0; rg < 4; ++rg) {
    const int o = 16 * ota + 4 * kq + rg;
    float* op = out + ((size_t)nb * 64 + o) * 512 + m * 128;
    op[d0] = acc0[rg];
    op[d1] = acc1[rg];
  }
}

extern "C" void kernel_launch(void* const* d_in, const int* in_sizes, int n_in,
                              void* d_out, int out_size, void* d_ws, size_t ws_size,
                              hipStream_t stream) {
  const float* x = (const float*)d_in[0];  // [64][1024][128] fp32
  const float* w = (const float*)d_in[1];  // [4][64][128] fp32
  float* out = (float*)d_out;              // [64][64][512] fp32
  ot_fused_kernel<<<256, 1024, 0, stream>>>(x, w, out);
}